// Round 1
// baseline (2340.002 us; speedup 1.0000x reference)
//
#include <hip/hip_runtime.h>
#include <hip/hip_bf16.h>
#include <math.h>

#define B_ 16
#define L_ 2048
#define H_ 768
#define INNER_ 384
#define MU_MAX_ 10.0f
#define LAM_ 0.1f

static __device__ __forceinline__ float wave_sum(float v) {
    #pragma unroll
    for (int o = 32; o > 0; o >>= 1) v += __shfl_xor(v, o, 64);
    return v;
}

// ---------------- GEMM: q = hidden @ wq + bq (fp32) ----------------
// M=32768, N=768, K=768. 128x64 tiles, 256 threads, 8x4 micro-tile.
#define BM 128
#define BN 64
#define BK 16
#define TM 8
#define TN 4

__global__ __launch_bounds__(256) void gemm_q_kernel(
    const float* __restrict__ A, const float* __restrict__ W,
    const float* __restrict__ bias, float* __restrict__ C)
{
    __shared__ float As[BK][BM + 4];   // k-major: conflict-free b128 reads
    __shared__ float Bs[BK][BN + 4];
    const int K = H_, N = H_;
    int m0 = blockIdx.x * BM;
    int n0 = blockIdx.y * BN;
    int t = threadIdx.x;
    int tn = t & 15, tm = t >> 4;
    float acc[TM][TN] = {};
    for (int k0 = 0; k0 < K; k0 += BK) {
        #pragma unroll
        for (int it = 0; it < 2; ++it) {
            int lin = t + it * 256;          // 0..511
            int mm = lin >> 2;               // 0..127
            int kk4 = (lin & 3) << 2;        // 0,4,8,12
            float4 a4 = *(const float4*)(A + (size_t)(m0 + mm) * K + k0 + kk4);
            As[kk4 + 0][mm] = a4.x;
            As[kk4 + 1][mm] = a4.y;
            As[kk4 + 2][mm] = a4.z;
            As[kk4 + 3][mm] = a4.w;
        }
        {
            int kk = t >> 4;                 // 0..15
            int nn4 = (t & 15) << 2;         // 0..60
            *(float4*)&Bs[kk][nn4] = *(const float4*)(W + (size_t)(k0 + kk) * N + n0 + nn4);
        }
        __syncthreads();
        #pragma unroll
        for (int k = 0; k < BK; ++k) {
            float a[TM], bb[TN];
            *(float4*)&a[0] = *(float4*)&As[k][tm * TM];
            *(float4*)&a[4] = *(float4*)&As[k][tm * TM + 4];
            *(float4*)&bb[0] = *(float4*)&Bs[k][tn * TN];
            #pragma unroll
            for (int i = 0; i < TM; ++i)
                #pragma unroll
                for (int j = 0; j < TN; ++j)
                    acc[i][j] = fmaf(a[i], bb[j], acc[i][j]);
        }
        __syncthreads();
    }
    float4 bv = *(const float4*)(bias + n0 + tn * TN);
    #pragma unroll
    for (int i = 0; i < TM; ++i) {
        int m = m0 + tm * TM + i;
        float4 o;
        o.x = acc[i][0] + bv.x;
        o.y = acc[i][1] + bv.y;
        o.z = acc[i][2] + bv.z;
        o.w = acc[i][3] + bv.w;
        *(float4*)(C + (size_t)m * N + n0 + tn * TN) = o;
    }
}

// ---------------- per-edge mu (one wave per (b,e)) ----------------
__global__ __launch_bounds__(256) void mu_kernel(
    const float* __restrict__ src, const int* __restrict__ ei, const int* __restrict__ ej,
    const float* __restrict__ w1, const float* __restrict__ b1,
    const float* __restrict__ w2, const float* __restrict__ b2,
    float* __restrict__ mu, int E)
{
    int gw = (blockIdx.x * 256 + threadIdx.x) >> 6;
    int lane = threadIdx.x & 63;
    if (gw >= B_ * E) return;   // uniform per wave
    int b = gw / E, e = gw - b * E;
    int i = ei[e], j = ej[e];
    const float4* ri = (const float4*)(src + ((size_t)b * L_ + i) * H_);
    const float4* rj = (const float4*)(src + ((size_t)b * L_ + j) * H_);
    float sii = 0.f, sjj = 0.f, sij = 0.f;
    #pragma unroll
    for (int it = 0; it < 3; ++it) {
        float4 xi = ri[it * 64 + lane];
        float4 xj = rj[it * 64 + lane];
        sii += xi.x*xi.x + xi.y*xi.y + xi.z*xi.z + xi.w*xi.w;
        sjj += xj.x*xj.x + xj.y*xj.y + xj.z*xj.z + xj.w*xj.w;
        sij += xi.x*xj.x + xi.y*xj.y + xi.z*xj.z + xi.w*xj.w;
    }
    sii = wave_sum(sii); sjj = wave_sum(sjj); sij = wave_sum(sij);
    float ni = fmaxf(sqrtf(sii), 1e-6f);
    float nj = fmaxf(sqrtf(sjj), 1e-6f);
    float dist = sqrtf(fmaxf(sii + sjj - 2.f * sij, 0.f));
    float cosv = sij / (ni * nj);
    float acc = 0.f;
    #pragma unroll
    for (int u0 = 0; u0 < INNER_; u0 += 64) {
        int u = u0 + lane;
        float z = fmaf(dist, w1[u], fmaf(cosv, w1[INNER_ + u], b1[u]));
        float g = 0.5f * z * (1.f + erff(z * 0.70710678118654752f)); // exact gelu
        acc = fmaf(g, w2[u], acc);
    }
    acc = wave_sum(acc);
    if (lane == 0) {
        float z = acc + b2[0];
        float sp = fmaxf(z, 0.f) + log1pf(expf(-fabsf(z)));  // stable softplus
        mu[gw] = fminf(sp + 1e-5f, MU_MAX_);
    }
}

// ---------------- Laplacian update: s1 = s - coef*(lap - q) ----------------
// mu layout: r=1 edges (i,i+1) at [0, L-1); r=2 edges (i,i+2) at [L-1, 2L-3)
__global__ __launch_bounds__(192) void lap_kernel(
    const float* __restrict__ src, const float* __restrict__ q,
    const float* __restrict__ mu, float* __restrict__ dst,
    float coef, int E)
{
    int bp = blockIdx.x;
    int b = bp >> 11, p = bp & (L_ - 1);
    const float* muB = mu + (size_t)b * E;
    auto mu1 = [&](int i) -> float { return (i >= 0 && i < L_ - 1) ? muB[i] : 0.f; };
    auto mu2 = [&](int i) -> float { return (i >= 0 && i < L_ - 2) ? muB[(L_ - 1) + i] : 0.f; };
    auto invf = [&](int pp) -> float {
        float deg = mu1(pp) + mu1(pp - 1) + mu2(pp) + mu2(pp - 2);
        return 1.f / sqrtf(fmaxf(deg, 1e-6f));
    };
    float inv_p = invf(p);
    const int dq[4] = {-2, -1, 1, 2};
    float w[4];
    float wsum = 0.f;
    #pragma unroll
    for (int k = 0; k < 4; ++k) {
        int dr = dq[k];
        int pq = p + dr;
        float m;
        if (dr == 1)       m = mu1(p);
        else if (dr == -1) m = mu1(p - 1);
        else if (dr == 2)  m = mu2(p);
        else               m = mu2(p - 2);
        float wv = 0.f;
        if (pq >= 0 && pq < L_) wv = m * inv_p * invf(pq);
        w[k] = wv;
        wsum += wv;
    }
    int c = threadIdx.x;  // 0..191 float4 lanes
    size_t rowbase = ((size_t)b * L_ + p) * H_;
    float4 sp = ((const float4*)(src + rowbase))[c];
    float4 lap;
    lap.x = sp.x * wsum; lap.y = sp.y * wsum; lap.z = sp.z * wsum; lap.w = sp.w * wsum;
    #pragma unroll
    for (int k = 0; k < 4; ++k) {
        int pq = min(max(p + dq[k], 0), L_ - 1);
        float4 sv = ((const float4*)(src + ((size_t)b * L_ + pq) * H_))[c];
        lap.x -= w[k] * sv.x;
        lap.y -= w[k] * sv.y;
        lap.z -= w[k] * sv.z;
        lap.w -= w[k] * sv.w;
    }
    float4 qq = ((const float4*)(q + rowbase))[c];
    float4 o;
    o.x = sp.x - coef * (lap.x - qq.x);
    o.y = sp.y - coef * (lap.y - qq.y);
    o.z = sp.z - coef * (lap.z - qq.z);
    o.w = sp.w - coef * (lap.w - qq.w);
    ((float4*)(dst + rowbase))[c] = o;
}

// ---------------- smoothing: s' = s1 - LAM*(2 s1 - left - right) ----------------
__global__ __launch_bounds__(192) void smooth_kernel(
    const float* __restrict__ s1, float* __restrict__ dst)
{
    int bp = blockIdx.x;
    int b = bp >> 11, p = bp & (L_ - 1);
    int pm = max(p - 1, 0), pp = min(p + 1, L_ - 1);
    int c = threadIdx.x;
    size_t rowbase = ((size_t)b * L_ + p) * H_;
    float4 x = ((const float4*)(s1 + rowbase))[c];
    float4 l = ((const float4*)(s1 + ((size_t)b * L_ + pm) * H_))[c];
    float4 r = ((const float4*)(s1 + ((size_t)b * L_ + pp) * H_))[c];
    float4 o;
    o.x = x.x - LAM_ * (2.f * x.x - l.x - r.x);
    o.y = x.y - LAM_ * (2.f * x.y - l.y - r.y);
    o.z = x.z - LAM_ * (2.f * x.z - l.z - r.z);
    o.w = x.w - LAM_ * (2.f * x.w - l.w - r.w);
    ((float4*)(dst + rowbase))[c] = o;
}

// ---------------- energy ----------------
__global__ void zero_energy_kernel(float* __restrict__ e) {
    if (threadIdx.x < B_) e[threadIdx.x] = 0.f;
}

__global__ __launch_bounds__(256) void energy_kernel(
    const float* __restrict__ state, const int* __restrict__ ei, const int* __restrict__ ej,
    const float* __restrict__ mu, float* __restrict__ energy, int E)
{
    int gw = (blockIdx.x * 256 + threadIdx.x) >> 6;
    int lane = threadIdx.x & 63;
    if (gw >= B_ * E) return;
    int b = gw / E, e = gw - b * E;
    int i = ei[e], j = ej[e];
    const float4* ri = (const float4*)(state + ((size_t)b * L_ + i) * H_);
    const float4* rj = (const float4*)(state + ((size_t)b * L_ + j) * H_);
    float s = 0.f;
    #pragma unroll
    for (int it = 0; it < 3; ++it) {
        float4 xi = ri[it * 64 + lane], xj = rj[it * 64 + lane];
        float dx = xi.x - xj.x, dy = xi.y - xj.y, dz = xi.z - xj.z, dw = xi.w - xj.w;
        s += dx*dx + dy*dy + dz*dz + dw*dw;
    }
    s = wave_sum(s);
    if (lane == 0) atomicAdd(energy + b, 0.5f * mu[gw] * s);
}

// ---------------- residual + LayerNorm ----------------
__global__ __launch_bounds__(192) void ln_kernel(
    const float* __restrict__ state, const float* __restrict__ hidden,
    const float* __restrict__ gamma, const float* __restrict__ beta,
    float* __restrict__ out)
{
    __shared__ float red[2][3];
    int bp = blockIdx.x;
    int c = threadIdx.x;
    size_t base = (size_t)bp * H_;
    float4 s4 = ((const float4*)(state + base))[c];
    float4 h4 = ((const float4*)(hidden + base))[c];
    float4 r;
    r.x = s4.x + h4.x; r.y = s4.y + h4.y; r.z = s4.z + h4.z; r.w = s4.w + h4.w;
    float sum = r.x + r.y + r.z + r.w;
    float sq  = r.x*r.x + r.y*r.y + r.z*r.z + r.w*r.w;
    sum = wave_sum(sum); sq = wave_sum(sq);
    int wid = c >> 6, lane = c & 63;
    if (lane == 0) { red[0][wid] = sum; red[1][wid] = sq; }
    __syncthreads();
    float S  = red[0][0] + red[0][1] + red[0][2];
    float SS = red[1][0] + red[1][1] + red[1][2];
    float mean = S * (1.f / H_);
    float var  = SS * (1.f / H_) - mean * mean;
    float rs = 1.f / sqrtf(var + 1e-5f);
    float4 g4 = ((const float4*)gamma)[c];
    float4 b4 = ((const float4*)beta)[c];
    float4 o;
    o.x = (r.x - mean) * rs * g4.x + b4.x;
    o.y = (r.y - mean) * rs * g4.y + b4.y;
    o.z = (r.z - mean) * rs * g4.z + b4.z;
    o.w = (r.w - mean) * rs * g4.w + b4.w;
    ((float4*)(out + base))[c] = o;
}

extern "C" void kernel_launch(void* const* d_in, const int* in_sizes, int n_in,
                              void* d_out, int out_size, void* d_ws, size_t ws_size,
                              hipStream_t stream)
{
    const float* hidden = (const float*)d_in[0];
    // d_in[1] attention_mask: all ones, unused by the reference math
    const float* w1 = (const float*)d_in[2];
    const float* b1 = (const float*)d_in[3];
    const float* w2 = (const float*)d_in[4];
    const float* b2 = (const float*)d_in[5];
    const float* wq = (const float*)d_in[6];
    const float* bq = (const float*)d_in[7];
    const float* gamma = (const float*)d_in[8];
    const float* beta  = (const float*)d_in[9];
    const int* ei = (const int*)d_in[10];
    const int* ej = (const int*)d_in[11];
    int E = in_sizes[10];   // 2L-3 = 4093

    const size_t BLH = (size_t)B_ * L_ * H_;
    float* out = (float*)d_out;
    float* energy = out + BLH;   // outputs concatenated: out (B,L,H) then energy (B,)

    // workspace: q | bufA | bufB | mu  (3*100.7MB + 256KB)
    float* q    = (float*)d_ws;
    float* bufA = q + BLH;
    float* bufB = bufA + BLH;
    float* mu   = bufB + BLH;

    gemm_q_kernel<<<dim3((B_ * L_) / BM, H_ / BN), 256, 0, stream>>>(hidden, wq, bq, q);
    zero_energy_kernel<<<1, 64, 0, stream>>>(energy);

    int nwaves = B_ * E;
    int mublocks = (nwaves + 3) / 4;   // 4 waves per 256-thread block
    const float* src = hidden;
    float coef = 0.1f;                 // ETA * 0.9^step
    for (int s = 0; s < 4; ++s) {
        mu_kernel<<<mublocks, 256, 0, stream>>>(src, ei, ej, w1, b1, w2, b2, mu, E);
        lap_kernel<<<B_ * L_, 192, 0, stream>>>(src, q, mu, bufA, coef, E);
        smooth_kernel<<<B_ * L_, 192, 0, stream>>>(bufA, bufB);
        src = bufB;
        coef *= 0.9f;
    }
    // energy uses final state but LAST step's mu (still in mu buffer)
    energy_kernel<<<mublocks, 256, 0, stream>>>(bufB, ei, ej, mu, energy, E);
    ln_kernel<<<B_ * L_, 192, 0, stream>>>(bufB, hidden, gamma, beta, out);
}

// Round 2
// 1548.542 us; speedup vs baseline: 1.5111x; 1.5111x over previous
//
#include <hip/hip_runtime.h>
#include <hip/hip_bf16.h>
#include <math.h>

#define B_ 16
#define L_ 2048
#define H_ 768
#define INNER_ 384
#define MU_MAX_ 10.0f
#define LAM_ 0.1f

static __device__ __forceinline__ float wave_sum(float v) {
    #pragma unroll
    for (int o = 32; o > 0; o >>= 1) v += __shfl_xor(v, o, 64);
    return v;
}

// ---------------- GEMM: q = hidden @ wq + bq (fp32) ----------------
// M=32768, N=768, K=768. 128x64 tiles, 256 threads, 8x4 micro-tile.
#define BM 128
#define BN 64
#define BK 16
#define TM 8
#define TN 4

__global__ __launch_bounds__(256) void gemm_q_kernel(
    const float* __restrict__ A, const float* __restrict__ W,
    const float* __restrict__ bias, float* __restrict__ C)
{
    __shared__ float As[BK][BM + 4];   // k-major: conflict-free b128 reads
    __shared__ float Bs[BK][BN + 4];
    const int K = H_, N = H_;
    int m0 = blockIdx.x * BM;
    int n0 = blockIdx.y * BN;
    int t = threadIdx.x;
    int tn = t & 15, tm = t >> 4;
    float acc[TM][TN] = {};
    for (int k0 = 0; k0 < K; k0 += BK) {
        #pragma unroll
        for (int it = 0; it < 2; ++it) {
            int lin = t + it * 256;          // 0..511
            int mm = lin >> 2;               // 0..127
            int kk4 = (lin & 3) << 2;        // 0,4,8,12
            float4 a4 = *(const float4*)(A + (size_t)(m0 + mm) * K + k0 + kk4);
            As[kk4 + 0][mm] = a4.x;
            As[kk4 + 1][mm] = a4.y;
            As[kk4 + 2][mm] = a4.z;
            As[kk4 + 3][mm] = a4.w;
        }
        {
            int kk = t >> 4;                 // 0..15
            int nn4 = (t & 15) << 2;         // 0..60
            *(float4*)&Bs[kk][nn4] = *(const float4*)(W + (size_t)(k0 + kk) * N + n0 + nn4);
        }
        __syncthreads();
        #pragma unroll
        for (int k = 0; k < BK; ++k) {
            float a[TM], bb[TN];
            *(float4*)&a[0] = *(float4*)&As[k][tm * TM];
            *(float4*)&a[4] = *(float4*)&As[k][tm * TM + 4];
            *(float4*)&bb[0] = *(float4*)&Bs[k][tn * TN];
            #pragma unroll
            for (int i = 0; i < TM; ++i)
                #pragma unroll
                for (int j = 0; j < TN; ++j)
                    acc[i][j] = fmaf(a[i], bb[j], acc[i][j]);
        }
        __syncthreads();
    }
    float4 bv = *(const float4*)(bias + n0 + tn * TN);
    #pragma unroll
    for (int i = 0; i < TM; ++i) {
        int m = m0 + tm * TM + i;
        float4 o;
        o.x = acc[i][0] + bv.x;
        o.y = acc[i][1] + bv.y;
        o.z = acc[i][2] + bv.z;
        o.w = acc[i][3] + bv.w;
        *(float4*)(C + (size_t)m * N + n0 + tn * TN) = o;
    }
}

// ---------------- per-edge mu (one wave per (b,e)) ----------------
__global__ __launch_bounds__(256) void mu_kernel(
    const float* __restrict__ src, const int* __restrict__ ei, const int* __restrict__ ej,
    const float* __restrict__ w1, const float* __restrict__ b1,
    const float* __restrict__ w2, const float* __restrict__ b2,
    float* __restrict__ mu, int E)
{
    int gw = (blockIdx.x * 256 + threadIdx.x) >> 6;
    int lane = threadIdx.x & 63;
    if (gw >= B_ * E) return;   // uniform per wave
    int b = gw / E, e = gw - b * E;
    int i = ei[e], j = ej[e];
    const float4* ri = (const float4*)(src + ((size_t)b * L_ + i) * H_);
    const float4* rj = (const float4*)(src + ((size_t)b * L_ + j) * H_);
    float sii = 0.f, sjj = 0.f, sij = 0.f;
    #pragma unroll
    for (int it = 0; it < 3; ++it) {
        float4 xi = ri[it * 64 + lane];
        float4 xj = rj[it * 64 + lane];
        sii += xi.x*xi.x + xi.y*xi.y + xi.z*xi.z + xi.w*xi.w;
        sjj += xj.x*xj.x + xj.y*xj.y + xj.z*xj.z + xj.w*xj.w;
        sij += xi.x*xj.x + xi.y*xj.y + xi.z*xj.z + xi.w*xj.w;
    }
    sii = wave_sum(sii); sjj = wave_sum(sjj); sij = wave_sum(sij);
    float ni = fmaxf(sqrtf(sii), 1e-6f);
    float nj = fmaxf(sqrtf(sjj), 1e-6f);
    float dist = sqrtf(fmaxf(sii + sjj - 2.f * sij, 0.f));
    float cosv = sij / (ni * nj);
    float acc = 0.f;
    #pragma unroll
    for (int u0 = 0; u0 < INNER_; u0 += 64) {
        int u = u0 + lane;
        float z = fmaf(dist, w1[u], fmaf(cosv, w1[INNER_ + u], b1[u]));
        float g = 0.5f * z * (1.f + erff(z * 0.70710678118654752f)); // exact gelu
        acc = fmaf(g, w2[u], acc);
    }
    acc = wave_sum(acc);
    if (lane == 0) {
        float z = acc + b2[0];
        float sp = fmaxf(z, 0.f) + log1pf(expf(-fabsf(z)));  // stable softplus
        mu[gw] = fminf(sp + 1e-5f, MU_MAX_);
    }
}

// ---------------- Laplacian update: s1 = s - coef*(lap - q) ----------------
// mu layout: r=1 edges (i,i+1) at [0, L-1); r=2 edges (i,i+2) at [L-1, 2L-3)
__global__ __launch_bounds__(192) void lap_kernel(
    const float* __restrict__ src, const float* __restrict__ q,
    const float* __restrict__ mu, float* __restrict__ dst,
    float coef, int E)
{
    int bp = blockIdx.x;
    int b = bp >> 11, p = bp & (L_ - 1);
    const float* muB = mu + (size_t)b * E;
    auto mu1 = [&](int i) -> float { return (i >= 0 && i < L_ - 1) ? muB[i] : 0.f; };
    auto mu2 = [&](int i) -> float { return (i >= 0 && i < L_ - 2) ? muB[(L_ - 1) + i] : 0.f; };
    auto invf = [&](int pp) -> float {
        float deg = mu1(pp) + mu1(pp - 1) + mu2(pp) + mu2(pp - 2);
        return 1.f / sqrtf(fmaxf(deg, 1e-6f));
    };
    float inv_p = invf(p);
    const int dq[4] = {-2, -1, 1, 2};
    float w[4];
    float wsum = 0.f;
    #pragma unroll
    for (int k = 0; k < 4; ++k) {
        int dr = dq[k];
        int pq = p + dr;
        float m;
        if (dr == 1)       m = mu1(p);
        else if (dr == -1) m = mu1(p - 1);
        else if (dr == 2)  m = mu2(p);
        else               m = mu2(p - 2);
        float wv = 0.f;
        if (pq >= 0 && pq < L_) wv = m * inv_p * invf(pq);
        w[k] = wv;
        wsum += wv;
    }
    int c = threadIdx.x;  // 0..191 float4 lanes
    size_t rowbase = ((size_t)b * L_ + p) * H_;
    float4 sp = ((const float4*)(src + rowbase))[c];
    float4 lap;
    lap.x = sp.x * wsum; lap.y = sp.y * wsum; lap.z = sp.z * wsum; lap.w = sp.w * wsum;
    #pragma unroll
    for (int k = 0; k < 4; ++k) {
        int pq = min(max(p + dq[k], 0), L_ - 1);
        float4 sv = ((const float4*)(src + ((size_t)b * L_ + pq) * H_))[c];
        lap.x -= w[k] * sv.x;
        lap.y -= w[k] * sv.y;
        lap.z -= w[k] * sv.z;
        lap.w -= w[k] * sv.w;
    }
    float4 qq = ((const float4*)(q + rowbase))[c];
    float4 o;
    o.x = sp.x - coef * (lap.x - qq.x);
    o.y = sp.y - coef * (lap.y - qq.y);
    o.z = sp.z - coef * (lap.z - qq.z);
    o.w = sp.w - coef * (lap.w - qq.w);
    ((float4*)(dst + rowbase))[c] = o;
}

// ---------------- smoothing: s' = s1 - LAM*(2 s1 - left - right) ----------------
__global__ __launch_bounds__(192) void smooth_kernel(
    const float* __restrict__ s1, float* __restrict__ dst)
{
    int bp = blockIdx.x;
    int b = bp >> 11, p = bp & (L_ - 1);
    int pm = max(p - 1, 0), pp = min(p + 1, L_ - 1);
    int c = threadIdx.x;
    size_t rowbase = ((size_t)b * L_ + p) * H_;
    float4 x = ((const float4*)(s1 + rowbase))[c];
    float4 l = ((const float4*)(s1 + ((size_t)b * L_ + pm) * H_))[c];
    float4 r = ((const float4*)(s1 + ((size_t)b * L_ + pp) * H_))[c];
    float4 o;
    o.x = x.x - LAM_ * (2.f * x.x - l.x - r.x);
    o.y = x.y - LAM_ * (2.f * x.y - l.y - r.y);
    o.z = x.z - LAM_ * (2.f * x.z - l.z - r.z);
    o.w = x.w - LAM_ * (2.f * x.w - l.w - r.w);
    ((float4*)(dst + rowbase))[c] = o;
}

// ---------------- energy ----------------
__global__ void zero_energy_kernel(float* __restrict__ e) {
    if (threadIdx.x < B_) e[threadIdx.x] = 0.f;
}

// One block = 64 edges of one batch (4 waves x 16 edges). One atomic per block
// -> 1024 atomics total (64 per address) instead of 65488 (4093 per address,
// which serialized at ~200ns each = the 833us we measured).
#define EPW 16
__global__ __launch_bounds__(256) void energy_kernel(
    const float* __restrict__ state, const int* __restrict__ ei, const int* __restrict__ ej,
    const float* __restrict__ mu, float* __restrict__ energy, int E)
{
    __shared__ float red[4];
    int wib = threadIdx.x >> 6;
    int lane = threadIdx.x & 63;
    int nchunk = (E + 63) / 64;
    int b = blockIdx.x / nchunk;
    int chunk = blockIdx.x - b * nchunk;
    int e0 = chunk * 64 + wib * EPW;
    const float* base = state + (size_t)b * L_ * H_;
    const float* muB = mu + (size_t)b * E;
    float part = 0.f;
    for (int k = 0; k < EPW; ++k) {
        int e = e0 + k;
        if (e >= E) break;
        int i = ei[e], j = ej[e];
        const float4* ri = (const float4*)(base + (size_t)i * H_);
        const float4* rj = (const float4*)(base + (size_t)j * H_);
        float s = 0.f;
        #pragma unroll
        for (int it = 0; it < 3; ++it) {
            float4 xi = ri[it * 64 + lane], xj = rj[it * 64 + lane];
            float dx = xi.x - xj.x, dy = xi.y - xj.y, dz = xi.z - xj.z, dw = xi.w - xj.w;
            s += dx*dx + dy*dy + dz*dz + dw*dw;
        }
        s = wave_sum(s);           // all lanes hold full sum (butterfly)
        part += muB[e] * s;
    }
    if (lane == 0) red[wib] = part;
    __syncthreads();
    if (threadIdx.x == 0)
        atomicAdd(energy + b, 0.5f * (red[0] + red[1] + red[2] + red[3]));
}

// ---------------- residual + LayerNorm ----------------
__global__ __launch_bounds__(192) void ln_kernel(
    const float* __restrict__ state, const float* __restrict__ hidden,
    const float* __restrict__ gamma, const float* __restrict__ beta,
    float* __restrict__ out)
{
    __shared__ float red[2][3];
    int bp = blockIdx.x;
    int c = threadIdx.x;
    size_t base = (size_t)bp * H_;
    float4 s4 = ((const float4*)(state + base))[c];
    float4 h4 = ((const float4*)(hidden + base))[c];
    float4 r;
    r.x = s4.x + h4.x; r.y = s4.y + h4.y; r.z = s4.z + h4.z; r.w = s4.w + h4.w;
    float sum = r.x + r.y + r.z + r.w;
    float sq  = r.x*r.x + r.y*r.y + r.z*r.z + r.w*r.w;
    sum = wave_sum(sum); sq = wave_sum(sq);
    int wid = c >> 6, lane = c & 63;
    if (lane == 0) { red[0][wid] = sum; red[1][wid] = sq; }
    __syncthreads();
    float S  = red[0][0] + red[0][1] + red[0][2];
    float SS = red[1][0] + red[1][1] + red[1][2];
    float mean = S * (1.f / H_);
    float var  = SS * (1.f / H_) - mean * mean;
    float rs = 1.f / sqrtf(var + 1e-5f);
    float4 g4 = ((const float4*)gamma)[c];
    float4 b4 = ((const float4*)beta)[c];
    float4 o;
    o.x = (r.x - mean) * rs * g4.x + b4.x;
    o.y = (r.y - mean) * rs * g4.y + b4.y;
    o.z = (r.z - mean) * rs * g4.z + b4.z;
    o.w = (r.w - mean) * rs * g4.w + b4.w;
    ((float4*)(out + base))[c] = o;
}

extern "C" void kernel_launch(void* const* d_in, const int* in_sizes, int n_in,
                              void* d_out, int out_size, void* d_ws, size_t ws_size,
                              hipStream_t stream)
{
    const float* hidden = (const float*)d_in[0];
    // d_in[1] attention_mask: all ones, unused by the reference math
    const float* w1 = (const float*)d_in[2];
    const float* b1 = (const float*)d_in[3];
    const float* w2 = (const float*)d_in[4];
    const float* b2 = (const float*)d_in[5];
    const float* wq = (const float*)d_in[6];
    const float* bq = (const float*)d_in[7];
    const float* gamma = (const float*)d_in[8];
    const float* beta  = (const float*)d_in[9];
    const int* ei = (const int*)d_in[10];
    const int* ej = (const int*)d_in[11];
    int E = in_sizes[10];   // 2L-3 = 4093

    const size_t BLH = (size_t)B_ * L_ * H_;
    float* out = (float*)d_out;
    float* energy = out + BLH;   // outputs concatenated: out (B,L,H) then energy (B,)

    // workspace: q | bufA | bufB | mu  (3*100.7MB + 256KB)
    float* q    = (float*)d_ws;
    float* bufA = q + BLH;
    float* bufB = bufA + BLH;
    float* mu   = bufB + BLH;

    gemm_q_kernel<<<dim3((B_ * L_) / BM, H_ / BN), 256, 0, stream>>>(hidden, wq, bq, q);
    zero_energy_kernel<<<1, 64, 0, stream>>>(energy);

    int nwaves = B_ * E;
    int mublocks = (nwaves + 3) / 4;   // 4 waves per 256-thread block
    const float* src = hidden;
    float coef = 0.1f;                 // ETA * 0.9^step
    for (int s = 0; s < 4; ++s) {
        mu_kernel<<<mublocks, 256, 0, stream>>>(src, ei, ej, w1, b1, w2, b2, mu, E);
        lap_kernel<<<B_ * L_, 192, 0, stream>>>(src, q, mu, bufA, coef, E);
        smooth_kernel<<<B_ * L_, 192, 0, stream>>>(bufA, bufB);
        src = bufB;
        coef *= 0.9f;
    }
    // energy uses final state but LAST step's mu (still in mu buffer)
    int nchunk = (E + 63) / 64;
    energy_kernel<<<B_ * nchunk, 256, 0, stream>>>(bufB, ei, ej, mu, energy, E);
    ln_kernel<<<B_ * L_, 192, 0, stream>>>(bufB, hidden, gamma, beta, out);
}

// Round 3
// 1168.372 us; speedup vs baseline: 2.0028x; 1.3254x over previous
//
#include <hip/hip_runtime.h>
#include <hip/hip_bf16.h>
#include <math.h>

#define B_ 16
#define L_ 2048
#define H_ 768
#define INNER_ 384
#define MU_MAX_ 10.0f
#define LAM_ 0.1f

typedef short v8bf __attribute__((ext_vector_type(8)));   // 8 bf16 (4 VGPRs)
typedef float v4f  __attribute__((ext_vector_type(4)));   // MFMA accumulator

static __device__ __forceinline__ float wave_sum(float v) {
    #pragma unroll
    for (int o = 32; o > 0; o >>= 1) v += __shfl_xor(v, o, 64);
    return v;
}

// round-to-nearest-even fp32 -> bf16 (matches numpy/JAX casting)
static __device__ __forceinline__ ushort f2bf(float x) {
    unsigned u = __float_as_uint(x);
    u += 0x7fffu + ((u >> 16) & 1u);
    return (ushort)(u >> 16);
}

// ---------------- convert hidden fp32 -> bf16 (8 elems/thread) ----------------
__global__ __launch_bounds__(256) void conv_bf16_kernel(
    const float* __restrict__ in, ushort* __restrict__ out, int n8)
{
    int t = blockIdx.x * 256 + threadIdx.x;
    if (t >= n8) return;
    float4 a = ((const float4*)in)[2 * t];
    float4 b = ((const float4*)in)[2 * t + 1];
    ushort r[8] = { f2bf(a.x), f2bf(a.y), f2bf(a.z), f2bf(a.w),
                    f2bf(b.x), f2bf(b.y), f2bf(b.z), f2bf(b.w) };
    ((v8bf*)out)[t] = *(v8bf*)r;
}

// ---------------- convert + transpose wq (K x N fp32) -> wt (N x K bf16) -------
__global__ __launch_bounds__(256) void conv_wqt_kernel(
    const float* __restrict__ wq, ushort* __restrict__ wt)
{
    __shared__ float tile[64][65];
    int k0 = blockIdx.x * 64, n0 = blockIdx.y * 64;
    int t = threadIdx.x;
    #pragma unroll
    for (int it = 0; it < 16; ++it) {
        int lin = t + it * 256;
        int r = lin >> 6, c = lin & 63;         // r: k, c: n  (coalesced read)
        tile[r][c] = wq[(size_t)(k0 + r) * H_ + n0 + c];
    }
    __syncthreads();
    #pragma unroll
    for (int it = 0; it < 16; ++it) {
        int lin = t + it * 256;
        int r = lin >> 6, c = lin & 63;         // r: n, c: k  (coalesced write)
        wt[(size_t)(n0 + r) * H_ + k0 + c] = f2bf(tile[c][r]);
    }
}

// ---------------- MFMA GEMM: q = A(bf16) @ wt^T + bq ----------------
// A: M x K row-major bf16; wt: N x K row-major bf16 (pre-transposed wq).
// 128x128 tile, BK=64, 256 threads = 4 waves in 2x2, each wave 4x4 of 16x16x32.
#define GBM 128
#define GBN 128
#define GBK 64
#define LSTR 72   // padded LDS row stride in bf16 (144B: 2-way bank alias = free)

__global__ __launch_bounds__(256) void gemm_q_kernel(
    const ushort* __restrict__ A, const ushort* __restrict__ Wt,
    const float* __restrict__ bias, float* __restrict__ C)
{
    __shared__ ushort As[GBM * LSTR];
    __shared__ ushort Bs[GBN * LSTR];
    const int K = H_, N = H_;
    int m0 = blockIdx.x * GBM;
    int n0 = blockIdx.y * GBN;
    int t = threadIdx.x;
    int lane = t & 63, w = t >> 6;
    int wm = (w & 1) * 64, wn = (w >> 1) * 64;
    int row16 = lane & 15, quad = lane >> 4;

    v4f acc[4][4];
    #pragma unroll
    for (int i = 0; i < 4; ++i)
        #pragma unroll
        for (int j = 0; j < 4; ++j)
            acc[i][j] = (v4f){0.f, 0.f, 0.f, 0.f};

    for (int k0 = 0; k0 < K; k0 += GBK) {
        // stage A and B tiles: 128 rows x 64 bf16 each = 1024 x 16B chunks
        #pragma unroll
        for (int it = 0; it < 4; ++it) {
            int lin = t + it * 256;           // 0..1023
            int r = lin >> 3;                 // row 0..127
            int s = lin & 7;                  // 16B segment 0..7
            *(v8bf*)&As[r * LSTR + s * 8] =
                *(const v8bf*)(A + (size_t)(m0 + r) * K + k0 + s * 8);
            *(v8bf*)&Bs[r * LSTR + s * 8] =
                *(const v8bf*)(Wt + (size_t)(n0 + r) * K + k0 + s * 8);
        }
        __syncthreads();
        #pragma unroll
        for (int h = 0; h < 2; ++h) {         // two K=32 halves
            v8bf af[4], bf[4];
            #pragma unroll
            for (int i = 0; i < 4; ++i)
                af[i] = *(v8bf*)&As[(wm + i * 16 + row16) * LSTR + h * 32 + quad * 8];
            #pragma unroll
            for (int j = 0; j < 4; ++j)
                bf[j] = *(v8bf*)&Bs[(wn + j * 16 + row16) * LSTR + h * 32 + quad * 8];
            #pragma unroll
            for (int i = 0; i < 4; ++i)
                #pragma unroll
                for (int j = 0; j < 4; ++j)
                    acc[i][j] = __builtin_amdgcn_mfma_f32_16x16x32_bf16(
                        af[i], bf[j], acc[i][j], 0, 0, 0);
        }
        __syncthreads();
    }
    // epilogue: C/D layout col=lane&15, row=quad*4+reg
    #pragma unroll
    for (int j = 0; j < 4; ++j) {
        int ncol = n0 + wn + j * 16 + row16;
        float bqv = bias[ncol];
        #pragma unroll
        for (int i = 0; i < 4; ++i) {
            int mrow = m0 + wm + i * 16 + quad * 4;
            #pragma unroll
            for (int r = 0; r < 4; ++r)
                C[(size_t)(mrow + r) * N + ncol] = acc[i][j][r] + bqv;
        }
    }
}

// ---------------- per-edge mu (one wave per (b,e)) ----------------
__global__ __launch_bounds__(256) void mu_kernel(
    const float* __restrict__ src, const int* __restrict__ ei, const int* __restrict__ ej,
    const float* __restrict__ w1, const float* __restrict__ b1,
    const float* __restrict__ w2, const float* __restrict__ b2,
    float* __restrict__ mu, int E)
{
    int gw = (blockIdx.x * 256 + threadIdx.x) >> 6;
    int lane = threadIdx.x & 63;
    if (gw >= B_ * E) return;   // uniform per wave
    int b = gw / E, e = gw - b * E;
    int i = ei[e], j = ej[e];
    const float4* ri = (const float4*)(src + ((size_t)b * L_ + i) * H_);
    const float4* rj = (const float4*)(src + ((size_t)b * L_ + j) * H_);
    float sii = 0.f, sjj = 0.f, sij = 0.f;
    #pragma unroll
    for (int it = 0; it < 3; ++it) {
        float4 xi = ri[it * 64 + lane];
        float4 xj = rj[it * 64 + lane];
        sii += xi.x*xi.x + xi.y*xi.y + xi.z*xi.z + xi.w*xi.w;
        sjj += xj.x*xj.x + xj.y*xj.y + xj.z*xj.z + xj.w*xj.w;
        sij += xi.x*xj.x + xi.y*xj.y + xi.z*xj.z + xi.w*xj.w;
    }
    sii = wave_sum(sii); sjj = wave_sum(sjj); sij = wave_sum(sij);
    float ni = fmaxf(sqrtf(sii), 1e-6f);
    float nj = fmaxf(sqrtf(sjj), 1e-6f);
    float dist = sqrtf(fmaxf(sii + sjj - 2.f * sij, 0.f));
    float cosv = sij / (ni * nj);
    float acc = 0.f;
    #pragma unroll
    for (int u0 = 0; u0 < INNER_; u0 += 64) {
        int u = u0 + lane;
        float z = fmaf(dist, w1[u], fmaf(cosv, w1[INNER_ + u], b1[u]));
        float g = 0.5f * z * (1.f + erff(z * 0.70710678118654752f)); // exact gelu
        acc = fmaf(g, w2[u], acc);
    }
    acc = wave_sum(acc);
    if (lane == 0) {
        float z = acc + b2[0];
        float sp = fmaxf(z, 0.f) + log1pf(expf(-fabsf(z)));  // stable softplus
        mu[gw] = fminf(sp + 1e-5f, MU_MAX_);
    }
}

// ---------------- Laplacian update: s1 = s - coef*(lap - q) ----------------
// mu layout: r=1 edges (i,i+1) at [0, L-1); r=2 edges (i,i+2) at [L-1, 2L-3)
__global__ __launch_bounds__(192) void lap_kernel(
    const float* __restrict__ src, const float* __restrict__ q,
    const float* __restrict__ mu, float* __restrict__ dst,
    float coef, int E)
{
    int bp = blockIdx.x;
    int b = bp >> 11, p = bp & (L_ - 1);
    const float* muB = mu + (size_t)b * E;
    auto mu1 = [&](int i) -> float { return (i >= 0 && i < L_ - 1) ? muB[i] : 0.f; };
    auto mu2 = [&](int i) -> float { return (i >= 0 && i < L_ - 2) ? muB[(L_ - 1) + i] : 0.f; };
    auto invf = [&](int pp) -> float {
        float deg = mu1(pp) + mu1(pp - 1) + mu2(pp) + mu2(pp - 2);
        return 1.f / sqrtf(fmaxf(deg, 1e-6f));
    };
    float inv_p = invf(p);
    const int dq[4] = {-2, -1, 1, 2};
    float w[4];
    float wsum = 0.f;
    #pragma unroll
    for (int k = 0; k < 4; ++k) {
        int dr = dq[k];
        int pq = p + dr;
        float m;
        if (dr == 1)       m = mu1(p);
        else if (dr == -1) m = mu1(p - 1);
        else if (dr == 2)  m = mu2(p);
        else               m = mu2(p - 2);
        float wv = 0.f;
        if (pq >= 0 && pq < L_) wv = m * inv_p * invf(pq);
        w[k] = wv;
        wsum += wv;
    }
    int c = threadIdx.x;  // 0..191 float4 lanes
    size_t rowbase = ((size_t)b * L_ + p) * H_;
    float4 sp = ((const float4*)(src + rowbase))[c];
    float4 lap;
    lap.x = sp.x * wsum; lap.y = sp.y * wsum; lap.z = sp.z * wsum; lap.w = sp.w * wsum;
    #pragma unroll
    for (int k = 0; k < 4; ++k) {
        int pq = min(max(p + dq[k], 0), L_ - 1);
        float4 sv = ((const float4*)(src + ((size_t)b * L_ + pq) * H_))[c];
        lap.x -= w[k] * sv.x;
        lap.y -= w[k] * sv.y;
        lap.z -= w[k] * sv.z;
        lap.w -= w[k] * sv.w;
    }
    float4 qq = ((const float4*)(q + rowbase))[c];
    float4 o;
    o.x = sp.x - coef * (lap.x - qq.x);
    o.y = sp.y - coef * (lap.y - qq.y);
    o.z = sp.z - coef * (lap.z - qq.z);
    o.w = sp.w - coef * (lap.w - qq.w);
    ((float4*)(dst + rowbase))[c] = o;
}

// ---------------- smoothing: s' = s1 - LAM*(2 s1 - left - right) ----------------
__global__ __launch_bounds__(192) void smooth_kernel(
    const float* __restrict__ s1, float* __restrict__ dst)
{
    int bp = blockIdx.x;
    int b = bp >> 11, p = bp & (L_ - 1);
    int pm = max(p - 1, 0), pp = min(p + 1, L_ - 1);
    int c = threadIdx.x;
    size_t rowbase = ((size_t)b * L_ + p) * H_;
    float4 x = ((const float4*)(s1 + rowbase))[c];
    float4 l = ((const float4*)(s1 + ((size_t)b * L_ + pm) * H_))[c];
    float4 r = ((const float4*)(s1 + ((size_t)b * L_ + pp) * H_))[c];
    float4 o;
    o.x = x.x - LAM_ * (2.f * x.x - l.x - r.x);
    o.y = x.y - LAM_ * (2.f * x.y - l.y - r.y);
    o.z = x.z - LAM_ * (2.f * x.z - l.z - r.z);
    o.w = x.w - LAM_ * (2.f * x.w - l.w - r.w);
    ((float4*)(dst + rowbase))[c] = o;
}

// ---------------- energy ----------------
__global__ void zero_energy_kernel(float* __restrict__ e) {
    if (threadIdx.x < B_) e[threadIdx.x] = 0.f;
}

// One block = 64 edges of one batch (4 waves x 16 edges). One atomic per block.
#define EPW 16
__global__ __launch_bounds__(256) void energy_kernel(
    const float* __restrict__ state, const int* __restrict__ ei, const int* __restrict__ ej,
    const float* __restrict__ mu, float* __restrict__ energy, int E)
{
    __shared__ float red[4];
    int wib = threadIdx.x >> 6;
    int lane = threadIdx.x & 63;
    int nchunk = (E + 63) / 64;
    int b = blockIdx.x / nchunk;
    int chunk = blockIdx.x - b * nchunk;
    int e0 = chunk * 64 + wib * EPW;
    const float* base = state + (size_t)b * L_ * H_;
    const float* muB = mu + (size_t)b * E;
    float part = 0.f;
    for (int k = 0; k < EPW; ++k) {
        int e = e0 + k;
        if (e >= E) break;
        int i = ei[e], j = ej[e];
        const float4* ri = (const float4*)(base + (size_t)i * H_);
        const float4* rj = (const float4*)(base + (size_t)j * H_);
        float s = 0.f;
        #pragma unroll
        for (int it = 0; it < 3; ++it) {
            float4 xi = ri[it * 64 + lane], xj = rj[it * 64 + lane];
            float dx = xi.x - xj.x, dy = xi.y - xj.y, dz = xi.z - xj.z, dw = xi.w - xj.w;
            s += dx*dx + dy*dy + dz*dz + dw*dw;
        }
        s = wave_sum(s);
        part += muB[e] * s;
    }
    if (lane == 0) red[wib] = part;
    __syncthreads();
    if (threadIdx.x == 0)
        atomicAdd(energy + b, 0.5f * (red[0] + red[1] + red[2] + red[3]));
}

// ---------------- residual + LayerNorm ----------------
__global__ __launch_bounds__(192) void ln_kernel(
    const float* __restrict__ state, const float* __restrict__ hidden,
    const float* __restrict__ gamma, const float* __restrict__ beta,
    float* __restrict__ out)
{
    __shared__ float red[2][3];
    int bp = blockIdx.x;
    int c = threadIdx.x;
    size_t base = (size_t)bp * H_;
    float4 s4 = ((const float4*)(state + base))[c];
    float4 h4 = ((const float4*)(hidden + base))[c];
    float4 r;
    r.x = s4.x + h4.x; r.y = s4.y + h4.y; r.z = s4.z + h4.z; r.w = s4.w + h4.w;
    float sum = r.x + r.y + r.z + r.w;
    float sq  = r.x*r.x + r.y*r.y + r.z*r.z + r.w*r.w;
    sum = wave_sum(sum); sq = wave_sum(sq);
    int wid = c >> 6, lane = c & 63;
    if (lane == 0) { red[0][wid] = sum; red[1][wid] = sq; }
    __syncthreads();
    float S  = red[0][0] + red[0][1] + red[0][2];
    float SS = red[1][0] + red[1][1] + red[1][2];
    float mean = S * (1.f / H_);
    float var  = SS * (1.f / H_) - mean * mean;
    float rs = 1.f / sqrtf(var + 1e-5f);
    float4 g4 = ((const float4*)gamma)[c];
    float4 b4 = ((const float4*)beta)[c];
    float4 o;
    o.x = (r.x - mean) * rs * g4.x + b4.x;
    o.y = (r.y - mean) * rs * g4.y + b4.y;
    o.z = (r.z - mean) * rs * g4.z + b4.z;
    o.w = (r.w - mean) * rs * g4.w + b4.w;
    ((float4*)(out + base))[c] = o;
}

extern "C" void kernel_launch(void* const* d_in, const int* in_sizes, int n_in,
                              void* d_out, int out_size, void* d_ws, size_t ws_size,
                              hipStream_t stream)
{
    const float* hidden = (const float*)d_in[0];
    // d_in[1] attention_mask: all ones, unused by the reference math
    const float* w1 = (const float*)d_in[2];
    const float* b1 = (const float*)d_in[3];
    const float* w2 = (const float*)d_in[4];
    const float* b2 = (const float*)d_in[5];
    const float* wq = (const float*)d_in[6];
    const float* bq = (const float*)d_in[7];
    const float* gamma = (const float*)d_in[8];
    const float* beta  = (const float*)d_in[9];
    const int* ei = (const int*)d_in[10];
    const int* ej = (const int*)d_in[11];
    int E = in_sizes[10];   // 2L-3 = 4093

    const size_t BLH = (size_t)B_ * L_ * H_;
    float* out = (float*)d_out;
    float* energy = out + BLH;   // outputs concatenated: out (B,L,H) then energy (B,)

    // workspace: q | bufA | bufB | mu | wt
    // A_bf16 aliases bufA's first half (dead once gemm finishes; lap step 0
    // overwrites bufA only after gemm completes on the stream).
    float* q    = (float*)d_ws;
    float* bufA = q + BLH;
    float* bufB = bufA + BLH;
    float* mu   = bufB + BLH;
    ushort* Abf = (ushort*)bufA;
    ushort* wt  = (ushort*)(mu + (size_t)B_ * E);

    int n8 = (int)(BLH / 8);
    conv_bf16_kernel<<<(n8 + 255) / 256, 256, 0, stream>>>(hidden, Abf, n8);
    conv_wqt_kernel<<<dim3(H_ / 64, H_ / 64), 256, 0, stream>>>(wq, wt);
    gemm_q_kernel<<<dim3((B_ * L_) / GBM, H_ / GBN), 256, 0, stream>>>(Abf, wt, bq, q);
    zero_energy_kernel<<<1, 64, 0, stream>>>(energy);

    int nwaves = B_ * E;
    int mublocks = (nwaves + 3) / 4;   // 4 waves per 256-thread block
    const float* src = hidden;
    float coef = 0.1f;                 // ETA * 0.9^step
    for (int s = 0; s < 4; ++s) {
        mu_kernel<<<mublocks, 256, 0, stream>>>(src, ei, ej, w1, b1, w2, b2, mu, E);
        lap_kernel<<<B_ * L_, 192, 0, stream>>>(src, q, mu, bufA, coef, E);
        smooth_kernel<<<B_ * L_, 192, 0, stream>>>(bufA, bufB);
        src = bufB;
        coef *= 0.9f;
    }
    // energy uses final state but LAST step's mu (still in mu buffer)
    int nchunk = (E + 63) / 64;
    energy_kernel<<<B_ * nchunk, 256, 0, stream>>>(bufB, ei, ej, mu, energy, E);
    ln_kernel<<<B_ * L_, 192, 0, stream>>>(bufB, hidden, gamma, beta, out);
}

// Round 4
// 1113.413 us; speedup vs baseline: 2.1016x; 1.0494x over previous
//
#include <hip/hip_runtime.h>
#include <hip/hip_bf16.h>
#include <math.h>

#define B_ 16
#define L_ 2048
#define H_ 768
#define INNER_ 384
#define MU_MAX_ 10.0f
#define LAM_ 0.1f

typedef short v8bf __attribute__((ext_vector_type(8)));   // 8 bf16 (4 VGPRs)
typedef float v4f  __attribute__((ext_vector_type(4)));   // MFMA accumulator

static __device__ __forceinline__ float wave_sum(float v) {
    #pragma unroll
    for (int o = 32; o > 0; o >>= 1) v += __shfl_xor(v, o, 64);
    return v;
}

// round-to-nearest-even fp32 -> bf16 (matches numpy/JAX casting)
static __device__ __forceinline__ ushort f2bf(float x) {
    unsigned u = __float_as_uint(x);
    u += 0x7fffu + ((u >> 16) & 1u);
    return (ushort)(u >> 16);
}

// ---------------- convert hidden fp32 -> bf16 (8 elems/thread) ----------------
__global__ __launch_bounds__(256) void conv_bf16_kernel(
    const float* __restrict__ in, ushort* __restrict__ out, int n8)
{
    int t = blockIdx.x * 256 + threadIdx.x;
    if (t >= n8) return;
    float4 a = ((const float4*)in)[2 * t];
    float4 b = ((const float4*)in)[2 * t + 1];
    ushort r[8] = { f2bf(a.x), f2bf(a.y), f2bf(a.z), f2bf(a.w),
                    f2bf(b.x), f2bf(b.y), f2bf(b.z), f2bf(b.w) };
    ((v8bf*)out)[t] = *(v8bf*)r;
}

// ---------------- convert + transpose wq (K x N fp32) -> wt (N x K bf16) -------
__global__ __launch_bounds__(256) void conv_wqt_kernel(
    const float* __restrict__ wq, ushort* __restrict__ wt)
{
    __shared__ float tile[64][65];
    int k0 = blockIdx.x * 64, n0 = blockIdx.y * 64;
    int t = threadIdx.x;
    #pragma unroll
    for (int it = 0; it < 16; ++it) {
        int lin = t + it * 256;
        int r = lin >> 6, c = lin & 63;         // r: k, c: n  (coalesced read)
        tile[r][c] = wq[(size_t)(k0 + r) * H_ + n0 + c];
    }
    __syncthreads();
    #pragma unroll
    for (int it = 0; it < 16; ++it) {
        int lin = t + it * 256;
        int r = lin >> 6, c = lin & 63;         // r: n, c: k  (coalesced write)
        wt[(size_t)(n0 + r) * H_ + k0 + c] = f2bf(tile[c][r]);
    }
}

// ---------------- MFMA GEMM: q = A(bf16) @ wt^T + bq ----------------
#define GBM 128
#define GBN 128
#define GBK 64
#define LSTR 72   // padded LDS row stride in bf16 (2-way bank alias = free)

__global__ __launch_bounds__(256) void gemm_q_kernel(
    const ushort* __restrict__ A, const ushort* __restrict__ Wt,
    const float* __restrict__ bias, float* __restrict__ C)
{
    __shared__ ushort As[GBM * LSTR];
    __shared__ ushort Bs[GBN * LSTR];
    const int K = H_, N = H_;
    int m0 = blockIdx.x * GBM;
    int n0 = blockIdx.y * GBN;
    int t = threadIdx.x;
    int lane = t & 63, w = t >> 6;
    int wm = (w & 1) * 64, wn = (w >> 1) * 64;
    int row16 = lane & 15, quad = lane >> 4;

    v4f acc[4][4];
    #pragma unroll
    for (int i = 0; i < 4; ++i)
        #pragma unroll
        for (int j = 0; j < 4; ++j)
            acc[i][j] = (v4f){0.f, 0.f, 0.f, 0.f};

    for (int k0 = 0; k0 < K; k0 += GBK) {
        #pragma unroll
        for (int it = 0; it < 4; ++it) {
            int lin = t + it * 256;           // 0..1023
            int r = lin >> 3;                 // row 0..127
            int s = lin & 7;                  // 16B segment 0..7
            *(v8bf*)&As[r * LSTR + s * 8] =
                *(const v8bf*)(A + (size_t)(m0 + r) * K + k0 + s * 8);
            *(v8bf*)&Bs[r * LSTR + s * 8] =
                *(const v8bf*)(Wt + (size_t)(n0 + r) * K + k0 + s * 8);
        }
        __syncthreads();
        #pragma unroll
        for (int h = 0; h < 2; ++h) {
            v8bf af[4], bf[4];
            #pragma unroll
            for (int i = 0; i < 4; ++i)
                af[i] = *(v8bf*)&As[(wm + i * 16 + row16) * LSTR + h * 32 + quad * 8];
            #pragma unroll
            for (int j = 0; j < 4; ++j)
                bf[j] = *(v8bf*)&Bs[(wn + j * 16 + row16) * LSTR + h * 32 + quad * 8];
            #pragma unroll
            for (int i = 0; i < 4; ++i)
                #pragma unroll
                for (int j = 0; j < 4; ++j)
                    acc[i][j] = __builtin_amdgcn_mfma_f32_16x16x32_bf16(
                        af[i], bf[j], acc[i][j], 0, 0, 0);
        }
        __syncthreads();
    }
    #pragma unroll
    for (int j = 0; j < 4; ++j) {
        int ncol = n0 + wn + j * 16 + row16;
        float bqv = bias[ncol];
        #pragma unroll
        for (int i = 0; i < 4; ++i) {
            int mrow = m0 + wm + i * 16 + quad * 4;
            #pragma unroll
            for (int r = 0; r < 4; ++r)
                C[(size_t)(mrow + r) * N + ncol] = acc[i][j][r] + bqv;
        }
    }
}

// ---------------- fused friction step ----------------
// Block = (batch b, 16-row chunk). Stages 26 src rows (chunk + halo 5 each side)
// in LDS, computes row norms + neighbor dots (wave reductions), mu via the MLP,
// deg/inv, lap+q update (s1, per-wave registers), writeback, smooth, store.
// mu written to global (packed: r=1 edges [0,L-1), r=2 at offset L-1) for energy.
#define RCHUNK 16
#define SROWS 26   // RCHUNK + 10 halo rows
#define SOFF 5     // base = r0 - SOFF

static __device__ __forceinline__ float mu_mlp(
    float si, float sj, float dotij,
    const float* __restrict__ w1, const float* __restrict__ b1,
    const float* __restrict__ w2, float b2v, int lane)
{
    float dist = sqrtf(fmaxf(si + sj - 2.f * dotij, 0.f));
    float cosv = dotij / (fmaxf(sqrtf(si), 1e-6f) * fmaxf(sqrtf(sj), 1e-6f));
    float acc = 0.f;
    #pragma unroll
    for (int u0 = 0; u0 < INNER_; u0 += 64) {
        int u = u0 + lane;
        float z = fmaf(dist, w1[u], fmaf(cosv, w1[INNER_ + u], b1[u]));
        float g = 0.5f * z * (1.f + erff(z * 0.70710678118654752f)); // exact gelu
        acc = fmaf(g, w2[u], acc);
    }
    acc = wave_sum(acc) + b2v;
    float sp = fmaxf(acc, 0.f) + log1pf(expf(-fabsf(acc)));  // stable softplus
    return fminf(sp + 1e-5f, MU_MAX_);
}

__global__ __launch_bounds__(192) void step_kernel(
    const float* __restrict__ src, const float* __restrict__ q,
    const float* __restrict__ w1, const float* __restrict__ b1,
    const float* __restrict__ w2, const float* __restrict__ b2,
    float* __restrict__ dst, float* __restrict__ muout,
    float coef, int E)
{
    __shared__ float rows[SROWS][H_];          // 79,872 B -> 2 blocks/CU
    __shared__ float ssA[SROWS], d1A[SROWS], d2A[SROWS];
    __shared__ float m1A[SROWS], m2A[SROWS], invA[SROWS];

    int blk = blockIdx.x;
    int chunk = (blk & 7) * 256 + (blk >> 3);  // XCD-contiguous chunk mapping
    int b = chunk >> 7;                        // chunk / (L/RCHUNK=128)
    int r0 = (chunk & 127) * RCHUNK;
    int base = r0 - SOFF;
    int t = threadIdx.x, wv = t >> 6, lane = t & 63;
    const float* srcB = src + (size_t)b * L_ * H_;
    const float* qB   = q   + (size_t)b * L_ * H_;
    float b2v = b2[0];

    // ---- stage 26 (clamped) src rows ----
    for (int s = wv; s < SROWS; s += 3) {
        int r = min(max(base + s, 0), L_ - 1);
        const float4* gp = (const float4*)(srcB + (size_t)r * H_);
        #pragma unroll
        for (int ch = 0; ch < 3; ++ch)
            *(float4*)&rows[s][ch * 256 + lane * 4] = gp[ch * 64 + lane];
    }
    __syncthreads();

    // ---- norms + neighbor dots ----
    for (int s = wv; s < SROWS; s += 3) {
        int s1i = min(s + 1, SROWS - 1), s2i = min(s + 2, SROWS - 1);
        float a0 = 0.f, a1 = 0.f, a2 = 0.f;
        #pragma unroll
        for (int ch = 0; ch < 3; ++ch) {
            int off = ch * 256 + lane * 4;
            float4 x = *(float4*)&rows[s][off];
            float4 y = *(float4*)&rows[s1i][off];
            float4 z = *(float4*)&rows[s2i][off];
            a0 += x.x*x.x + x.y*x.y + x.z*x.z + x.w*x.w;
            a1 += x.x*y.x + x.y*y.y + x.z*y.z + x.w*y.w;
            a2 += x.x*z.x + x.y*z.y + x.z*z.z + x.w*z.w;
        }
        a0 = wave_sum(a0); a1 = wave_sum(a1); a2 = wave_sum(a2);
        if (lane == 0) { ssA[s] = a0; d1A[s] = a1; d2A[s] = a2; }
    }
    __syncthreads();

    // ---- mu via MLP (zero for invalid edges) ----
    for (int s = wv; s < SROWS; s += 3) {
        int e = base + s;
        float v1 = 0.f, v2 = 0.f;
        if (e >= 0 && e < L_ - 1 && s + 1 < SROWS)
            v1 = mu_mlp(ssA[s], ssA[s + 1], d1A[s], w1, b1, w2, b2v, lane);
        if (e >= 0 && e < L_ - 2 && s + 2 < SROWS)
            v2 = mu_mlp(ssA[s], ssA[s + 2], d2A[s], w1, b1, w2, b2v, lane);
        if (lane == 0) {
            m1A[s] = v1; m2A[s] = v2;
            if (e >= r0 && e < r0 + RCHUNK) {      // each valid edge covered once
                if (e >= 0 && e < L_ - 1) muout[(size_t)b * E + e] = v1;
                if (e >= 0 && e < L_ - 2) muout[(size_t)b * E + (L_ - 1) + e] = v2;
            }
        }
    }
    __syncthreads();

    // ---- deg -> inv (invalid-edge mus are 0, matching reference deg) ----
    if (t >= 2 && t < SROWS) {
        float deg = m1A[t] + m1A[t - 1] + m2A[t] + m2A[t - 2];
        invA[t] = 1.f / sqrtf(fmaxf(deg, 1e-6f));
    }
    __syncthreads();

    // ---- s1 = src - coef*(lap - q), rows [r0-1, r0+RCHUNK] into registers ----
    float4 s1r[6][3];
    bool vld[6];
    #pragma unroll
    for (int k = 0; k < 6; ++k) {
        int sst = 4 + wv * 6 + k;        // slots 4..21 (18 rows)
        int tt = base + sst;
        vld[k] = (tt >= 0 && tt < L_);
        if (!vld[k]) continue;
        float invp = invA[sst];
        float wm2 = m2A[sst - 2] * invp * invA[sst - 2];
        float wm1 = m1A[sst - 1] * invp * invA[sst - 1];
        float wp1 = m1A[sst]     * invp * invA[sst + 1];
        float wp2 = m2A[sst]     * invp * invA[sst + 2];
        float wsum = wm2 + wm1 + wp1 + wp2;
        const float4* qp = (const float4*)(qB + (size_t)tt * H_);
        #pragma unroll
        for (int ch = 0; ch < 3; ++ch) {
            int off = ch * 256 + lane * 4;
            float4 x   = *(float4*)&rows[sst][off];
            float4 xm2 = *(float4*)&rows[sst - 2][off];
            float4 xm1 = *(float4*)&rows[sst - 1][off];
            float4 xp1 = *(float4*)&rows[sst + 1][off];
            float4 xp2 = *(float4*)&rows[sst + 2][off];
            float4 qq  = qp[ch * 64 + lane];
            float4 o;
            o.x = x.x - coef * (wsum*x.x - wm2*xm2.x - wm1*xm1.x - wp1*xp1.x - wp2*xp2.x - qq.x);
            o.y = x.y - coef * (wsum*x.y - wm2*xm2.y - wm1*xm1.y - wp1*xp1.y - wp2*xp2.y - qq.y);
            o.z = x.z - coef * (wsum*x.z - wm2*xm2.z - wm1*xm1.z - wp1*xp1.z - wp2*xp2.z - qq.z);
            o.w = x.w - coef * (wsum*x.w - wm2*xm2.w - wm1*xm1.w - wp1*xp1.w - wp2*xp2.w - qq.w);
            s1r[k][ch] = o;
        }
    }
    __syncthreads();   // everyone done reading src slots
    #pragma unroll
    for (int k = 0; k < 6; ++k) {
        if (!vld[k]) continue;
        int sst = 4 + wv * 6 + k;
        #pragma unroll
        for (int ch = 0; ch < 3; ++ch)
            *(float4*)&rows[sst][ch * 256 + lane * 4] = s1r[k][ch];
    }
    __syncthreads();

    // ---- smooth + store ----
    #pragma unroll
    for (int k = 0; k < 6; ++k) {
        int idx = wv * 6 + k;
        if (idx >= RCHUNK) break;        // uniform per wave
        int p = r0 + idx;
        int sp  = p - base;
        int spm = max(p - 1, 0) - base;
        int spp = min(p + 1, L_ - 1) - base;
        float4* op = (float4*)(dst + ((size_t)b * L_ + p) * H_);
        #pragma unroll
        for (int ch = 0; ch < 3; ++ch) {
            int off = ch * 256 + lane * 4;
            float4 x = *(float4*)&rows[sp][off];
            float4 l = *(float4*)&rows[spm][off];
            float4 r = *(float4*)&rows[spp][off];
            float4 o;
            o.x = x.x - LAM_ * (2.f * x.x - l.x - r.x);
            o.y = x.y - LAM_ * (2.f * x.y - l.y - r.y);
            o.z = x.z - LAM_ * (2.f * x.z - l.z - r.z);
            o.w = x.w - LAM_ * (2.f * x.w - l.w - r.w);
            op[ch * 64 + lane] = o;
        }
    }
}

// ---------------- energy ----------------
__global__ void zero_energy_kernel(float* __restrict__ e) {
    if (threadIdx.x < B_) e[threadIdx.x] = 0.f;
}

// One block = 64 edges of one batch (4 waves x 16 edges). One atomic per block.
#define EPW 16
__global__ __launch_bounds__(256) void energy_kernel(
    const float* __restrict__ state, const int* __restrict__ ei, const int* __restrict__ ej,
    const float* __restrict__ mu, float* __restrict__ energy, int E)
{
    __shared__ float red[4];
    int wib = threadIdx.x >> 6;
    int lane = threadIdx.x & 63;
    int nchunk = (E + 63) / 64;
    int b = blockIdx.x / nchunk;
    int chunk = blockIdx.x - b * nchunk;
    int e0 = chunk * 64 + wib * EPW;
    const float* base = state + (size_t)b * L_ * H_;
    const float* muB = mu + (size_t)b * E;
    float part = 0.f;
    for (int k = 0; k < EPW; ++k) {
        int e = e0 + k;
        if (e >= E) break;
        int i = ei[e], j = ej[e];
        const float4* ri = (const float4*)(base + (size_t)i * H_);
        const float4* rj = (const float4*)(base + (size_t)j * H_);
        float s = 0.f;
        #pragma unroll
        for (int it = 0; it < 3; ++it) {
            float4 xi = ri[it * 64 + lane], xj = rj[it * 64 + lane];
            float dx = xi.x - xj.x, dy = xi.y - xj.y, dz = xi.z - xj.z, dw = xi.w - xj.w;
            s += dx*dx + dy*dy + dz*dz + dw*dw;
        }
        s = wave_sum(s);
        part += muB[e] * s;
    }
    if (lane == 0) red[wib] = part;
    __syncthreads();
    if (threadIdx.x == 0)
        atomicAdd(energy + b, 0.5f * (red[0] + red[1] + red[2] + red[3]));
}

// ---------------- residual + LayerNorm ----------------
__global__ __launch_bounds__(192) void ln_kernel(
    const float* __restrict__ state, const float* __restrict__ hidden,
    const float* __restrict__ gamma, const float* __restrict__ beta,
    float* __restrict__ out)
{
    __shared__ float red[2][3];
    int bp = blockIdx.x;
    int c = threadIdx.x;
    size_t base = (size_t)bp * H_;
    float4 s4 = ((const float4*)(state + base))[c];
    float4 h4 = ((const float4*)(hidden + base))[c];
    float4 r;
    r.x = s4.x + h4.x; r.y = s4.y + h4.y; r.z = s4.z + h4.z; r.w = s4.w + h4.w;
    float sum = r.x + r.y + r.z + r.w;
    float sq  = r.x*r.x + r.y*r.y + r.z*r.z + r.w*r.w;
    sum = wave_sum(sum); sq = wave_sum(sq);
    int wid = c >> 6, lane = c & 63;
    if (lane == 0) { red[0][wid] = sum; red[1][wid] = sq; }
    __syncthreads();
    float S  = red[0][0] + red[0][1] + red[0][2];
    float SS = red[1][0] + red[1][1] + red[1][2];
    float mean = S * (1.f / H_);
    float var  = SS * (1.f / H_) - mean * mean;
    float rs = 1.f / sqrtf(var + 1e-5f);
    float4 g4 = ((const float4*)gamma)[c];
    float4 b4 = ((const float4*)beta)[c];
    float4 o;
    o.x = (r.x - mean) * rs * g4.x + b4.x;
    o.y = (r.y - mean) * rs * g4.y + b4.y;
    o.z = (r.z - mean) * rs * g4.z + b4.z;
    o.w = (r.w - mean) * rs * g4.w + b4.w;
    ((float4*)(out + base))[c] = o;
}

extern "C" void kernel_launch(void* const* d_in, const int* in_sizes, int n_in,
                              void* d_out, int out_size, void* d_ws, size_t ws_size,
                              hipStream_t stream)
{
    const float* hidden = (const float*)d_in[0];
    // d_in[1] attention_mask: all ones, unused by the reference math
    const float* w1 = (const float*)d_in[2];
    const float* b1 = (const float*)d_in[3];
    const float* w2 = (const float*)d_in[4];
    const float* b2 = (const float*)d_in[5];
    const float* wq = (const float*)d_in[6];
    const float* bq = (const float*)d_in[7];
    const float* gamma = (const float*)d_in[8];
    const float* beta  = (const float*)d_in[9];
    const int* ei = (const int*)d_in[10];
    const int* ej = (const int*)d_in[11];
    int E = in_sizes[10];   // 2L-3 = 4093

    const size_t BLH = (size_t)B_ * L_ * H_;
    float* out = (float*)d_out;
    float* energy = out + BLH;   // outputs concatenated: out (B,L,H) then energy (B,)

    // workspace: q | bufA | bufB | mu | wt
    float* q    = (float*)d_ws;
    float* bufA = q + BLH;
    float* bufB = bufA + BLH;
    float* mu   = bufB + BLH;
    ushort* Abf = (ushort*)bufA;         // aliases bufA (dead after gemm)
    ushort* wt  = (ushort*)(mu + (size_t)B_ * E);

    int n8 = (int)(BLH / 8);
    conv_bf16_kernel<<<(n8 + 255) / 256, 256, 0, stream>>>(hidden, Abf, n8);
    conv_wqt_kernel<<<dim3(H_ / 64, H_ / 64), 256, 0, stream>>>(wq, wt);
    gemm_q_kernel<<<dim3((B_ * L_) / GBM, H_ / GBN), 256, 0, stream>>>(Abf, wt, bq, q);
    zero_energy_kernel<<<1, 64, 0, stream>>>(energy);

    const int nblk = B_ * (L_ / RCHUNK);   // 2048
    float coef = 0.1f;                     // ETA * 0.9^step
    step_kernel<<<nblk, 192, 0, stream>>>(hidden, q, w1, b1, w2, b2, bufA, mu, coef, E);
    coef *= 0.9f;
    step_kernel<<<nblk, 192, 0, stream>>>(bufA, q, w1, b1, w2, b2, bufB, mu, coef, E);
    coef *= 0.9f;
    step_kernel<<<nblk, 192, 0, stream>>>(bufB, q, w1, b1, w2, b2, bufA, mu, coef, E);
    coef *= 0.9f;
    step_kernel<<<nblk, 192, 0, stream>>>(bufA, q, w1, b1, w2, b2, bufB, mu, coef, E);

    int nchunk = (E + 63) / 64;
    energy_kernel<<<B_ * nchunk, 256, 0, stream>>>(bufB, ei, ej, mu, energy, E);
    ln_kernel<<<B_ * L_, 192, 0, stream>>>(bufB, hidden, gamma, beta, out);
}